// Round 1
// baseline (1407.593 us; speedup 1.0000x reference)
//
#include <hip/hip_runtime.h>

#define CH 128      // OUT_SIZE * HEADS
#define KIN 128     // IN_SIZE

// ---------------- K1: Zp = Z @ W^T + b  -> [N, 128] ----------------
// Block: 128 threads, tile 32 nodes x 128 cols, per-thread 4 nodes x 8 cols.
__global__ __launch_bounds__(128) void k_gemm(const float* __restrict__ Z,
                                              const float* __restrict__ W,
                                              const float* __restrict__ b,
                                              float* __restrict__ Zp, int N)
{
    __shared__ float lZ[32][36];    // [node][k] pad to 36 (144B rows, 16B aligned)
    __shared__ float lW[32][132];   // [k][c]   pad to 132 (528B rows, 16B aligned)
    const int tid = threadIdx.x;
    const int c_t = tid & 15;        // 16 col-threads
    const int n_t = tid >> 4;        // 8 node-threads
    const int c0 = c_t * 8;
    const int nb0 = blockIdx.x * 32;

    float4 accA[4], accB[4];
    const float4 bA = *(const float4*)(b + c0);
    const float4 bB = *(const float4*)(b + c0 + 4);
#pragma unroll
    for (int n = 0; n < 4; n++) { accA[n] = bA; accB[n] = bB; }

    for (int k0 = 0; k0 < KIN; k0 += 32) {
        // stage Z tile: 32 nodes x 32 k
#pragma unroll
        for (int r = 0; r < 2; r++) {
            int idx = tid + r * 128;       // 0..255 float4 slots
            int n   = idx >> 3;            // 0..31
            int kk  = (idx & 7) * 4;
            int gn  = nb0 + n; if (gn >= N) gn = N - 1;
            float4 v = *(const float4*)(Z + (size_t)gn * KIN + k0 + kk);
            *(float4*)(&lZ[n][kk]) = v;
        }
        // stage W^T tile: lW[kk][c] = W[c][k0+kk]
#pragma unroll
        for (int r = 0; r < 8; r++) {
            int idx = tid + r * 128;       // 0..1023
            int c   = idx >> 3;            // 0..127
            int kk  = (idx & 7) * 4;
            float4 v = *(const float4*)(W + (size_t)c * KIN + k0 + kk);
            lW[kk + 0][c] = v.x; lW[kk + 1][c] = v.y;
            lW[kk + 2][c] = v.z; lW[kk + 3][c] = v.w;
        }
        __syncthreads();
#pragma unroll
        for (int kk = 0; kk < 32; kk += 4) {
            float4 z[4];
#pragma unroll
            for (int n = 0; n < 4; n++) z[n] = *(float4*)(&lZ[n_t * 4 + n][kk]);
#pragma unroll
            for (int j = 0; j < 4; j++) {
                float4 wa = *(float4*)(&lW[kk + j][c0]);
                float4 wb = *(float4*)(&lW[kk + j][c0 + 4]);
#pragma unroll
                for (int n = 0; n < 4; n++) {
                    float zs = (j == 0) ? z[n].x : (j == 1) ? z[n].y : (j == 2) ? z[n].z : z[n].w;
                    accA[n].x += zs * wa.x; accA[n].y += zs * wa.y;
                    accA[n].z += zs * wa.z; accA[n].w += zs * wa.w;
                    accB[n].x += zs * wb.x; accB[n].y += zs * wb.y;
                    accB[n].z += zs * wb.z; accB[n].w += zs * wb.w;
                }
            }
        }
        __syncthreads();
    }
#pragma unroll
    for (int n = 0; n < 4; n++) {
        int gn = nb0 + n_t * 4 + n;
        if (gn < N) {
            *(float4*)(Zp + (size_t)gn * CH + c0)     = accA[n];
            *(float4*)(Zp + (size_t)gn * CH + c0 + 4) = accB[n];
        }
    }
}

// ---------------- K1b: e_l[n,h] = sum_o Zp[n,o*4+h]*a_l[o*4+h] ----------------
__global__ __launch_bounds__(256) void k_logits(const float* __restrict__ Zp,
                                                const float* __restrict__ al,
                                                const float* __restrict__ ar,
                                                float* __restrict__ el,
                                                float* __restrict__ er, int N)
{
    int wave = threadIdx.x >> 6;
    int lane = threadIdx.x & 63;
    int node = blockIdx.x * 4 + wave;
    if (node >= N) return;
    float z1 = Zp[(size_t)node * CH + lane];
    float z2 = Zp[(size_t)node * CH + 64 + lane];
    float vl = z1 * al[lane] + z2 * al[64 + lane];
    float vr = z1 * ar[lane] + z2 * ar[64 + lane];
#pragma unroll
    for (int m = 4; m <= 32; m <<= 1) {
        vl += __shfl_xor(vl, m, 64);
        vr += __shfl_xor(vr, m, 64);
    }
    if (lane < 4) {
        el[node * 4 + lane] = vl;
        er[node * 4 + lane] = vr;
    }
}

// monotonic float<->uint encoding for atomicMax on floats (handles negatives)
__device__ __forceinline__ unsigned encf(float f) {
    unsigned u = __float_as_uint(f);
    return (u & 0x80000000u) ? ~u : (u | 0x80000000u);
}
__device__ __forceinline__ float decf(unsigned u) {
    return __uint_as_float((u & 0x80000000u) ? (u ^ 0x80000000u) : ~u);
}

// ---------------- K2: edge logits + segment max over dst ----------------
__global__ __launch_bounds__(256) void k_edge_max(const int* __restrict__ idx,
                                                  const float* __restrict__ el,
                                                  const float* __restrict__ er,
                                                  float* __restrict__ aex,
                                                  unsigned* __restrict__ mEnc, int E)
{
    int e = blockIdx.x * 256 + threadIdx.x;
    if (e >= E) return;
    int src = idx[e], dst = idx[E + e];
    float4 l = *(const float4*)(el + (size_t)src * 4);
    float4 r = *(const float4*)(er + (size_t)dst * 4);
    float4 a;
    a.x = l.x + r.x; a.y = l.y + r.y; a.z = l.z + r.z; a.w = l.w + r.w;
    a.x = a.x > 0.f ? a.x : 0.01f * a.x;
    a.y = a.y > 0.f ? a.y : 0.01f * a.y;
    a.z = a.z > 0.f ? a.z : 0.01f * a.z;
    a.w = a.w > 0.f ? a.w : 0.01f * a.w;
    *(float4*)(aex + (size_t)e * 4) = a;
    atomicMax(&mEnc[dst * 4 + 0], encf(a.x));
    atomicMax(&mEnc[dst * 4 + 1], encf(a.y));
    atomicMax(&mEnc[dst * 4 + 2], encf(a.z));
    atomicMax(&mEnc[dst * 4 + 3], encf(a.w));
}

// ---------------- K3: ex = exp(a - m[dst]); segment sum ----------------
__global__ __launch_bounds__(256) void k_edge_exp(const int* __restrict__ idx,
                                                  float* __restrict__ aex,
                                                  const unsigned* __restrict__ mEnc,
                                                  float* __restrict__ s, int E)
{
    int e = blockIdx.x * 256 + threadIdx.x;
    if (e >= E) return;
    int dst = idx[E + e];
    uint4  m = *(const uint4*)(mEnc + (size_t)dst * 4);
    float4 a = *(float4*)(aex + (size_t)e * 4);
    float4 ex;
    ex.x = __expf(a.x - decf(m.x));
    ex.y = __expf(a.y - decf(m.y));
    ex.z = __expf(a.z - decf(m.z));
    ex.w = __expf(a.w - decf(m.w));
    *(float4*)(aex + (size_t)e * 4) = ex;
    atomicAdd(&s[dst * 4 + 0], ex.x);
    atomicAdd(&s[dst * 4 + 1], ex.y);
    atomicAdd(&s[dst * 4 + 2], ex.z);
    atomicAdd(&s[dst * 4 + 3], ex.w);
}

// ---------------- K3b: s -> 1/s ----------------
__global__ __launch_bounds__(256) void k_inv(float* __restrict__ s, int n)
{
    int i = blockIdx.x * 256 + threadIdx.x;
    if (i < n) s[i] = 1.0f / s[i];
}

// ---------------- K4: out[src,c] += att[e, c&3] * Zp[dst, c] ----------------
__global__ __launch_bounds__(256) void k_scatter(const int* __restrict__ idx,
                                                 const float* __restrict__ aex,
                                                 const float* __restrict__ sinv,
                                                 const float* __restrict__ Zp,
                                                 float* __restrict__ out, int E)
{
    int gid = blockIdx.x * 256 + threadIdx.x;
    if (gid >= E * CH) return;   // E*128 = 204.8M < 2^31
    int e = gid >> 7;
    int c = gid & 127;
    int h = c & 3;
    int src = idx[e], dst = idx[E + e];
    float att = aex[(size_t)e * 4 + h] * sinv[(size_t)dst * 4 + h];
    atomicAdd(out + (size_t)src * CH + c, att * Zp[(size_t)dst * CH + c]);
}

extern "C" void kernel_launch(void* const* d_in, const int* in_sizes, int n_in,
                              void* d_out, int out_size, void* d_ws, size_t ws_size,
                              hipStream_t stream)
{
    const int*   idx = (const int*)d_in[0];
    const float* Z   = (const float*)d_in[2];
    const float* W   = (const float*)d_in[3];
    const float* b   = (const float*)d_in[4];
    const float* al  = (const float*)d_in[5];
    const float* ar  = (const float*)d_in[6];
    float* out = (float*)d_out;

    const int E = in_sizes[0] / 2;
    const int N = in_sizes[2] / KIN;

    char* ws = (char*)d_ws;
    float*    Zp   = (float*)ws;                                  // N*128 f32
    float*    el   = (float*)(ws + (size_t)N * CH * 4);           // N*4
    float*    er   = el + (size_t)N * 4;                          // N*4
    unsigned* mEnc = (unsigned*)(er + (size_t)N * 4);             // N*4
    float*    s    = (float*)(mEnc + (size_t)N * 4);              // N*4
    float*    aex  = s + (size_t)N * 4;                           // E*4

    hipMemsetAsync(mEnc, 0, (size_t)N * 4 * sizeof(unsigned), stream);
    hipMemsetAsync(s,    0, (size_t)N * 4 * sizeof(float), stream);
    hipMemsetAsync(out,  0, (size_t)out_size * sizeof(float), stream);

    k_gemm<<<(N + 31) / 32, 128, 0, stream>>>(Z, W, b, Zp, N);
    k_logits<<<(N + 3) / 4, 256, 0, stream>>>(Zp, al, ar, el, er, N);
    k_edge_max<<<(E + 255) / 256, 256, 0, stream>>>(idx, el, er, aex, mEnc, E);
    k_edge_exp<<<(E + 255) / 256, 256, 0, stream>>>(idx, aex, mEnc, s, E);
    k_inv<<<(N * 4 + 255) / 256, 256, 0, stream>>>(s, N * 4);
    {
        long long total = (long long)E * CH;
        int grid = (int)((total + 255) / 256);
        k_scatter<<<grid, 256, 0, stream>>>(idx, aex, s, Zp, out, E);
    }
}

// Round 2
// 1027.501 us; speedup vs baseline: 1.3699x; 1.3699x over previous
//
#include <hip/hip_runtime.h>
#include <math.h>

#define CH 128      // OUT_SIZE * HEADS
#define KIN 128     // IN_SIZE

// ---------------- K1: Zp = Z @ W^T + b  -> [N, 128] ----------------
__global__ __launch_bounds__(128) void k_gemm(const float* __restrict__ Z,
                                              const float* __restrict__ W,
                                              const float* __restrict__ b,
                                              float* __restrict__ Zp, int N)
{
    __shared__ float lZ[32][36];
    __shared__ float lW[32][132];
    const int tid = threadIdx.x;
    const int c_t = tid & 15;
    const int n_t = tid >> 4;
    const int c0 = c_t * 8;
    const int nb0 = blockIdx.x * 32;

    float4 accA[4], accB[4];
    const float4 bA = *(const float4*)(b + c0);
    const float4 bB = *(const float4*)(b + c0 + 4);
#pragma unroll
    for (int n = 0; n < 4; n++) { accA[n] = bA; accB[n] = bB; }

    for (int k0 = 0; k0 < KIN; k0 += 32) {
#pragma unroll
        for (int r = 0; r < 2; r++) {
            int idx = tid + r * 128;
            int n   = idx >> 3;
            int kk  = (idx & 7) * 4;
            int gn  = nb0 + n; if (gn >= N) gn = N - 1;
            float4 v = *(const float4*)(Z + (size_t)gn * KIN + k0 + kk);
            *(float4*)(&lZ[n][kk]) = v;
        }
#pragma unroll
        for (int r = 0; r < 8; r++) {
            int idx = tid + r * 128;
            int c   = idx >> 3;
            int kk  = (idx & 7) * 4;
            float4 v = *(const float4*)(W + (size_t)c * KIN + k0 + kk);
            lW[kk + 0][c] = v.x; lW[kk + 1][c] = v.y;
            lW[kk + 2][c] = v.z; lW[kk + 3][c] = v.w;
        }
        __syncthreads();
#pragma unroll
        for (int kk = 0; kk < 32; kk += 4) {
            float4 z[4];
#pragma unroll
            for (int n = 0; n < 4; n++) z[n] = *(float4*)(&lZ[n_t * 4 + n][kk]);
#pragma unroll
            for (int j = 0; j < 4; j++) {
                float4 wa = *(float4*)(&lW[kk + j][c0]);
                float4 wb = *(float4*)(&lW[kk + j][c0 + 4]);
#pragma unroll
                for (int n = 0; n < 4; n++) {
                    float zs = (j == 0) ? z[n].x : (j == 1) ? z[n].y : (j == 2) ? z[n].z : z[n].w;
                    accA[n].x += zs * wa.x; accA[n].y += zs * wa.y;
                    accA[n].z += zs * wa.z; accA[n].w += zs * wa.w;
                    accB[n].x += zs * wb.x; accB[n].y += zs * wb.y;
                    accB[n].z += zs * wb.z; accB[n].w += zs * wb.w;
                }
            }
        }
        __syncthreads();
    }
#pragma unroll
    for (int n = 0; n < 4; n++) {
        int gn = nb0 + n_t * 4 + n;
        if (gn < N) {
            *(float4*)(Zp + (size_t)gn * CH + c0)     = accA[n];
            *(float4*)(Zp + (size_t)gn * CH + c0 + 4) = accB[n];
        }
    }
}

// ---------------- K1b: per-node attention logits ----------------
__global__ __launch_bounds__(256) void k_logits(const float* __restrict__ Zp,
                                                const float* __restrict__ al,
                                                const float* __restrict__ ar,
                                                float* __restrict__ el,
                                                float* __restrict__ er, int N)
{
    int wave = threadIdx.x >> 6;
    int lane = threadIdx.x & 63;
    int node = blockIdx.x * 4 + wave;
    if (node >= N) return;
    float z1 = Zp[(size_t)node * CH + lane];
    float z2 = Zp[(size_t)node * CH + 64 + lane];
    float vl = z1 * al[lane] + z2 * al[64 + lane];
    float vr = z1 * ar[lane] + z2 * ar[64 + lane];
#pragma unroll
    for (int m = 4; m <= 32; m <<= 1) {
        vl += __shfl_xor(vl, m, 64);
        vr += __shfl_xor(vr, m, 64);
    }
    if (lane < 4) {
        el[node * 4 + lane] = vl;
        er[node * 4 + lane] = vr;
    }
}

// ---------------- K2: degree count (src + dst) ----------------
__global__ __launch_bounds__(256) void k_degree(const int* __restrict__ idx,
                                                int* __restrict__ deg_src,
                                                int* __restrict__ deg_dst, int E)
{
    int e = blockIdx.x * 256 + threadIdx.x;
    if (e >= E) return;
    atomicAdd(&deg_src[idx[e]], 1);
    atomicAdd(&deg_dst[idx[E + e]], 1);
}

// ---------------- K3: single-block exclusive scan of n degrees ----------------
__global__ __launch_bounds__(1024) void k_scan(const int* __restrict__ deg,
                                               int* __restrict__ offs,
                                               int* __restrict__ cur, int n)
{
    __shared__ int part[1024];
    int t = threadIdx.x;
    int chunk = (n + 1023) >> 10;
    int lo = t * chunk;
    int hi = min(lo + chunk, n);
    int s = 0;
    for (int i = lo; i < hi; i++) s += deg[i];
    part[t] = s;
    __syncthreads();
    for (int off = 1; off < 1024; off <<= 1) {
        int v = (t >= off) ? part[t - off] : 0;
        __syncthreads();
        part[t] += v;
        __syncthreads();
    }
    int run = (t == 0) ? 0 : part[t - 1];
    for (int i = lo; i < hi; i++) {
        offs[i] = run; cur[i] = run; run += deg[i];
    }
    if (t == 1023) offs[n] = part[1023];
}

// ---------------- K4: fill CSR edge lists ----------------
__global__ __launch_bounds__(256) void k_fill(const int* __restrict__ idx,
                                              int* __restrict__ cur_src,
                                              int* __restrict__ cur_dst,
                                              int* __restrict__ list_src,
                                              int* __restrict__ list_dst, int E)
{
    int e = blockIdx.x * 256 + threadIdx.x;
    if (e >= E) return;
    int s = idx[e], d = idx[E + e];
    list_src[atomicAdd(&cur_src[s], 1)] = e;
    list_dst[atomicAdd(&cur_dst[d], 1)] = e;
}

// ---------------- K5: segment softmax by dst (one wave per node) ----------------
// lane = (q, h): q = lane>>2 in [0,16) edge slot, h = lane&3 head
__global__ __launch_bounds__(256) void k_softmax(const int* __restrict__ idx,
                                                 const float* __restrict__ el,
                                                 const float* __restrict__ er,
                                                 const int* __restrict__ offs_dst,
                                                 const int* __restrict__ list_dst,
                                                 float* __restrict__ att, int N, int E)
{
    int wave = threadIdx.x >> 6;
    int lane = threadIdx.x & 63;
    int node = blockIdx.x * 4 + wave;
    if (node >= N) return;
    int start = offs_dst[node], end = offs_dst[node + 1];
    if (start == end) return;
    int h = lane & 3, q = lane >> 2;
    float er_h = er[(size_t)node * 4 + h];
    float m = -INFINITY, s = 0.f;
    // pass 1: compute leaky logits, stash to att[], online (m,s) per lane
    for (int j0 = start; j0 < end; j0 += 16) {
        int j = j0 + q;
        if (j < end) {
            int e = list_dst[j];
            int sn = idx[e];
            float a = el[(size_t)sn * 4 + h] + er_h;
            a = a > 0.f ? a : 0.01f * a;
            att[(size_t)e * 4 + h] = a;
            if (a > m) { s = s * __expf(m - a) + 1.f; m = a; }
            else        s += __expf(a - m);
        }
    }
    // merge the 16 lanes sharing head h (xor over quad strides)
#pragma unroll
    for (int mask = 4; mask <= 32; mask <<= 1) {
        float mo = __shfl_xor(m, mask, 64);
        float so = __shfl_xor(s, mask, 64);
        float mn = fmaxf(m, mo);
        if (mn > -INFINITY)
            s = s * __expf(m - mn) + so * __expf(mo - mn);
        m = mn;
    }
    float sinv = 1.0f / s;
    // pass 2: normalize
    for (int j0 = start; j0 < end; j0 += 16) {
        int j = j0 + q;
        if (j < end) {
            int e = list_dst[j];
            float a = att[(size_t)e * 4 + h];
            att[(size_t)e * 4 + h] = __expf(a - m) * sinv;
        }
    }
}

// ---------------- K6: gather by src (one wave per node, no atomics) ----------------
// lane holds cols {lane, lane+64}; head of both = lane&3
__global__ __launch_bounds__(256) void k_gather(const int* __restrict__ idx,
                                                const float* __restrict__ att,
                                                const float* __restrict__ Zp,
                                                const int* __restrict__ offs_src,
                                                const int* __restrict__ list_src,
                                                float* __restrict__ out, int N, int E)
{
    int wave = threadIdx.x >> 6;
    int lane = threadIdx.x & 63;
    int node = blockIdx.x * 4 + wave;
    if (node >= N) return;
    int start = offs_src[node], end = offs_src[node + 1];
    int h = lane & 3;
    float acc0 = 0.f, acc1 = 0.f;
    int j = start;
    for (; j + 1 < end; j += 2) {
        int e0 = list_src[j], e1 = list_src[j + 1];
        int d0 = idx[E + e0], d1 = idx[E + e1];
        float at0 = att[(size_t)e0 * 4 + h];
        float at1 = att[(size_t)e1 * 4 + h];
        float z00 = Zp[(size_t)d0 * CH + lane];
        float z01 = Zp[(size_t)d0 * CH + 64 + lane];
        float z10 = Zp[(size_t)d1 * CH + lane];
        float z11 = Zp[(size_t)d1 * CH + 64 + lane];
        acc0 += at0 * z00 + at1 * z10;
        acc1 += at0 * z01 + at1 * z11;
    }
    if (j < end) {
        int e0 = list_src[j];
        int d0 = idx[E + e0];
        float at0 = att[(size_t)e0 * 4 + h];
        acc0 += at0 * Zp[(size_t)d0 * CH + lane];
        acc1 += at0 * Zp[(size_t)d0 * CH + 64 + lane];
    }
    out[(size_t)node * CH + lane]      = acc0;
    out[(size_t)node * CH + 64 + lane] = acc1;
}

extern "C" void kernel_launch(void* const* d_in, const int* in_sizes, int n_in,
                              void* d_out, int out_size, void* d_ws, size_t ws_size,
                              hipStream_t stream)
{
    const int*   idx = (const int*)d_in[0];
    const float* Z   = (const float*)d_in[2];
    const float* W   = (const float*)d_in[3];
    const float* b   = (const float*)d_in[4];
    const float* al  = (const float*)d_in[5];
    const float* ar  = (const float*)d_in[6];
    float* out = (float*)d_out;

    const int E = in_sizes[0] / 2;
    const int N = in_sizes[2] / KIN;

    // workspace layout (floats then ints), all 16B-aligned
    float* Zp  = (float*)d_ws;                          // N*128
    float* el  = Zp + (size_t)N * CH;                   // N*4
    float* er  = el + (size_t)N * 4;                    // N*4
    float* att = er + (size_t)N * 4;                    // E*4
    int* deg_src  = (int*)(att + (size_t)E * 4);        // N
    int* deg_dst  = deg_src + N;                        // N
    int* offs_src = deg_dst + N;                        // N+1
    int* offs_dst = offs_src + (N + 1);                 // N+1
    int* cur_src  = offs_dst + (N + 1);                 // N
    int* cur_dst  = cur_src + N;                        // N
    int* list_src = cur_dst + N;                        // E
    int* list_dst = list_src + E;                       // E

    hipMemsetAsync(deg_src, 0, (size_t)2 * N * sizeof(int), stream);

    k_gemm  <<<(N + 31) / 32, 128, 0, stream>>>(Z, W, b, Zp, N);
    k_logits<<<(N + 3) / 4,   256, 0, stream>>>(Zp, al, ar, el, er, N);
    k_degree<<<(E + 255) / 256, 256, 0, stream>>>(idx, deg_src, deg_dst, E);
    k_scan  <<<1, 1024, 0, stream>>>(deg_src, offs_src, cur_src, N);
    k_scan  <<<1, 1024, 0, stream>>>(deg_dst, offs_dst, cur_dst, N);
    k_fill  <<<(E + 255) / 256, 256, 0, stream>>>(idx, cur_src, cur_dst, list_src, list_dst, E);
    k_softmax<<<(N + 3) / 4, 256, 0, stream>>>(idx, el, er, offs_dst, list_dst, att, N, E);
    k_gather <<<(N + 3) / 4, 256, 0, stream>>>(idx, att, Zp, offs_src, list_src, out, N, E);
}

// Round 3
// 382.823 us; speedup vs baseline: 3.6769x; 2.6840x over previous
//
#include <hip/hip_runtime.h>
#include <math.h>

#define CH 128      // OUT_SIZE * HEADS
#define KIN 128     // IN_SIZE
#define BH 128      // histogram / coarse-scatter block count
#define FCAP 4096   // max edges per 64-node bucket handled in LDS (mean 2046, sd 45)

// ---------------- K1: Zp = Z @ W^T + b  -> [N, 128] ----------------
__global__ __launch_bounds__(128) void k_gemm(const float* __restrict__ Z,
                                              const float* __restrict__ W,
                                              const float* __restrict__ b,
                                              float* __restrict__ Zp, int N)
{
    __shared__ float lZ[32][36];
    __shared__ float lW[32][132];
    const int tid = threadIdx.x;
    const int c_t = tid & 15;
    const int n_t = tid >> 4;
    const int c0 = c_t * 8;
    const int nb0 = blockIdx.x * 32;

    float4 accA[4], accB[4];
    const float4 bA = *(const float4*)(b + c0);
    const float4 bB = *(const float4*)(b + c0 + 4);
#pragma unroll
    for (int n = 0; n < 4; n++) { accA[n] = bA; accB[n] = bB; }

    for (int k0 = 0; k0 < KIN; k0 += 32) {
#pragma unroll
        for (int r = 0; r < 2; r++) {
            int idx = tid + r * 128;
            int n   = idx >> 3;
            int kk  = (idx & 7) * 4;
            int gn  = nb0 + n; if (gn >= N) gn = N - 1;
            float4 v = *(const float4*)(Z + (size_t)gn * KIN + k0 + kk);
            *(float4*)(&lZ[n][kk]) = v;
        }
#pragma unroll
        for (int r = 0; r < 8; r++) {
            int idx = tid + r * 128;
            int c   = idx >> 3;
            int kk  = (idx & 7) * 4;
            float4 v = *(const float4*)(W + (size_t)c * KIN + k0 + kk);
            lW[kk + 0][c] = v.x; lW[kk + 1][c] = v.y;
            lW[kk + 2][c] = v.z; lW[kk + 3][c] = v.w;
        }
        __syncthreads();
#pragma unroll
        for (int kk = 0; kk < 32; kk += 4) {
            float4 z[4];
#pragma unroll
            for (int n = 0; n < 4; n++) z[n] = *(float4*)(&lZ[n_t * 4 + n][kk]);
#pragma unroll
            for (int j = 0; j < 4; j++) {
                float4 wa = *(float4*)(&lW[kk + j][c0]);
                float4 wb = *(float4*)(&lW[kk + j][c0 + 4]);
#pragma unroll
                for (int n = 0; n < 4; n++) {
                    float zs = (j == 0) ? z[n].x : (j == 1) ? z[n].y : (j == 2) ? z[n].z : z[n].w;
                    accA[n].x += zs * wa.x; accA[n].y += zs * wa.y;
                    accA[n].z += zs * wa.z; accA[n].w += zs * wa.w;
                    accB[n].x += zs * wb.x; accB[n].y += zs * wb.y;
                    accB[n].z += zs * wb.z; accB[n].w += zs * wb.w;
                }
            }
        }
        __syncthreads();
    }
#pragma unroll
    for (int n = 0; n < 4; n++) {
        int gn = nb0 + n_t * 4 + n;
        if (gn < N) {
            *(float4*)(Zp + (size_t)gn * CH + c0)     = accA[n];
            *(float4*)(Zp + (size_t)gn * CH + c0 + 4) = accB[n];
        }
    }
}

// ---------------- K1b: per-node attention logits ----------------
__global__ __launch_bounds__(256) void k_logits(const float* __restrict__ Zp,
                                                const float* __restrict__ al,
                                                const float* __restrict__ ar,
                                                float* __restrict__ el,
                                                float* __restrict__ er, int N)
{
    int wave = threadIdx.x >> 6;
    int lane = threadIdx.x & 63;
    int node = blockIdx.x * 4 + wave;
    if (node >= N) return;
    float z1 = Zp[(size_t)node * CH + lane];
    float z2 = Zp[(size_t)node * CH + 64 + lane];
    float vl = z1 * al[lane] + z2 * al[64 + lane];
    float vr = z1 * ar[lane] + z2 * ar[64 + lane];
#pragma unroll
    for (int m = 4; m <= 32; m <<= 1) {
        vl += __shfl_xor(vl, m, 64);
        vr += __shfl_xor(vr, m, 64);
    }
    if (lane < 4) {
        el[node * 4 + lane] = vl;
        er[node * 4 + lane] = vr;
    }
}

// ---------------- K2: per-block bucket histograms (both sides in one pass) ----------------
// H layout: [side(2)][bucket(NBK)][block(BH)]
__global__ __launch_bounds__(256) void k_hist(const int* __restrict__ idx,
                                              int* __restrict__ H, int E, int NBK)
{
    __shared__ int lc[2 * 1024];
    int b = blockIdx.x, t = threadIdx.x;
    for (int i = t; i < 2 * NBK; i += 256) lc[i] = 0;
    __syncthreads();
    int chunk = (E + BH - 1) / BH;
    int lo = b * chunk, hi = min(lo + chunk, E);
    for (int e = lo + t; e < hi; e += 256) {
        int s = idx[e], d = idx[E + e];
        atomicAdd(&lc[s >> 6], 1);
        atomicAdd(&lc[NBK + (d >> 6)], 1);
    }
    __syncthreads();
    for (int i = t; i < 2 * NBK; i += 256) H[(size_t)i * BH + b] = lc[i];
}

// ---------------- K3a: per-bucket totals ----------------
__global__ __launch_bounds__(128) void k_bsum(const int* __restrict__ H,
                                              int* __restrict__ btot)
{
    int i = blockIdx.x, t = threadIdx.x;
    int v = H[(size_t)i * BH + t];
#pragma unroll
    for (int m = 1; m < 64; m <<= 1) v += __shfl_xor(v, m, 64);
    __shared__ int w0;
    if (t == 0) w0 = v;
    __syncthreads();
    if (t == 64) btot[i] = w0 + v;
}

// ---------------- K3b: single-block exclusive scan (n <= ~2048) ----------------
__global__ __launch_bounds__(1024) void k_scan(const int* __restrict__ deg,
                                               int* __restrict__ offs, int n)
{
    __shared__ int part[1024];
    int t = threadIdx.x;
    int chunk = (n + 1023) >> 10;
    int lo = t * chunk;
    int hi = min(lo + chunk, n);
    int s = 0;
    for (int i = lo; i < hi; i++) s += deg[i];
    part[t] = s;
    __syncthreads();
    for (int off = 1; off < 1024; off <<= 1) {
        int v = (t >= off) ? part[t - off] : 0;
        __syncthreads();
        part[t] += v;
        __syncthreads();
    }
    int run = (t == 0) ? 0 : part[t - 1];
    for (int i = lo; i < hi; i++) { offs[i] = run; run += deg[i]; }
    if (t == 1023) offs[n] = part[1023];
}

// ---------------- K3c: per-bucket block bases (exclusive scan of 128 + bucket base) ----------------
__global__ __launch_bounds__(128) void k_bbase(int* __restrict__ H,
                                               const int* __restrict__ bbase)
{
    int i = blockIdx.x, t = threadIdx.x;
    int v = H[(size_t)i * BH + t];
    __shared__ int part[128];
    part[t] = v;
    __syncthreads();
    for (int off = 1; off < 128; off <<= 1) {
        int u = (t >= off) ? part[t - off] : 0;
        __syncthreads();
        part[t] += u;
        __syncthreads();
    }
    H[(size_t)i * BH + t] = (t == 0 ? 0 : part[t - 1]) + bbase[i];
}

// ---------------- K4: coarse scatter into bucket-sorted array ----------------
// payload: (node&63)<<26 | other_node (other_node < 65536)
__global__ __launch_bounds__(256) void k_coarse(const int* __restrict__ idx,
                                                const int* __restrict__ H,
                                                unsigned* __restrict__ C,
                                                int E, int NBK)
{
    __shared__ int lc[2 * 1024];
    int b = blockIdx.x, t = threadIdx.x;
    for (int i = t; i < 2 * NBK; i += 256) lc[i] = H[(size_t)i * BH + b];
    __syncthreads();
    int chunk = (E + BH - 1) / BH;
    int lo = b * chunk, hi = min(lo + chunk, E);
    for (int e = lo + t; e < hi; e += 256) {
        int s = idx[e], d = idx[E + e];
        int p = atomicAdd(&lc[s >> 6], 1);
        C[p] = ((unsigned)(s & 63) << 26) | (unsigned)d;
        int p2 = atomicAdd(&lc[NBK + (d >> 6)], 1);
        C[p2] = ((unsigned)(d & 63) << 26) | (unsigned)s;
    }
}

// ---------------- K5: fine sort within bucket (LDS) + node offsets ----------------
__global__ __launch_bounds__(256) void k_fine(const unsigned* __restrict__ C,
                                              const int* __restrict__ bbase,
                                              unsigned short* __restrict__ FS,
                                              unsigned short* __restrict__ FD,
                                              int* __restrict__ offs_src,
                                              int* __restrict__ offs_dst,
                                              int E, int N, int NBK)
{
    __shared__ unsigned pay[FCAP];
    __shared__ unsigned short srt[FCAP];
    __shared__ int cnt[64], loffs[64], rnk[64];
    int i = blockIdx.x, t = threadIdx.x;
    int side = (i >= NBK) ? 1 : 0;
    int k = i - side * NBK;
    int start = bbase[i], end = bbase[i + 1];
    int count = end - start;
    int rel = start - side * E;
    unsigned short* out = side ? FD : FS;
    int* offs = side ? offs_dst : offs_src;
    if (t < 64) { cnt[t] = 0; rnk[t] = 0; }
    __syncthreads();

    if (count <= FCAP) {
        for (int p = t; p < count; p += 256) {
            unsigned v = C[start + p];
            pay[p] = v;
            atomicAdd(&cnt[v >> 26], 1);
        }
        __syncthreads();
        if (t < 64) {
            int v = cnt[t], inc = v;
#pragma unroll
            for (int m = 1; m < 64; m <<= 1) {
                int u = __shfl_up(inc, m, 64);
                if (t >= m) inc += u;
            }
            loffs[t] = inc - v;
        }
        __syncthreads();
        if (t < 64) {
            int node = k * 64 + t;
            if (node <= N) offs[node] = rel + loffs[t];
        }
        for (int p = t; p < count; p += 256) {
            unsigned v = pay[p];
            int n6 = v >> 26;
            int r = atomicAdd(&rnk[n6], 1);
            srt[loffs[n6] + r] = (unsigned short)(v & 0xFFFFu);
        }
        __syncthreads();
        for (int p = t; p < count; p += 256) out[rel + p] = srt[p];
    } else {
        // fallback (statistically unreachable): two passes over global C
        for (int p = t; p < count; p += 256) atomicAdd(&cnt[C[start + p] >> 26], 1);
        __syncthreads();
        if (t < 64) {
            int v = cnt[t], inc = v;
#pragma unroll
            for (int m = 1; m < 64; m <<= 1) {
                int u = __shfl_up(inc, m, 64);
                if (t >= m) inc += u;
            }
            loffs[t] = inc - v;
        }
        __syncthreads();
        if (t < 64) {
            int node = k * 64 + t;
            if (node <= N) offs[node] = rel + loffs[t];
        }
        for (int p = t; p < count; p += 256) {
            unsigned v = C[start + p];
            int n6 = v >> 26;
            int r = atomicAdd(&rnk[n6], 1);
            out[rel + loffs[n6] + r] = (unsigned short)(v & 0xFFFFu);
        }
    }
}

// ---------------- K6: dst-side online softmax stats -> mx, sv(=1/sum) ----------------
// lane = (q, h): q = lane>>2 edge slot, h = lane&3 head
__global__ __launch_bounds__(256) void k_softmax(const unsigned short* __restrict__ FD,
                                                 const int* __restrict__ offs_dst,
                                                 const float* __restrict__ el,
                                                 const float* __restrict__ er,
                                                 float* __restrict__ mx,
                                                 float* __restrict__ sv, int N)
{
    int wave = threadIdx.x >> 6;
    int lane = threadIdx.x & 63;
    int node = blockIdx.x * 4 + wave;
    if (node >= N) return;
    int start = offs_dst[node], end = offs_dst[node + 1];
    int h = lane & 3, q = lane >> 2;
    float er_h = er[node * 4 + h];
    float m = -INFINITY, s = 0.f;
    for (int j = start + q; j < end; j += 16) {
        int src = FD[j];
        float a = el[src * 4 + h] + er_h;
        a = a > 0.f ? a : 0.01f * a;
        if (a > m) { s = s * __expf(m - a) + 1.f; m = a; }
        else         s += __expf(a - m);
    }
#pragma unroll
    for (int mask = 4; mask <= 32; mask <<= 1) {
        float mo = __shfl_xor(m, mask, 64);
        float so = __shfl_xor(s, mask, 64);
        float mn = fmaxf(m, mo);
        if (mn > -INFINITY)
            s = s * __expf(m - mn) + so * __expf(mo - mn);
        m = mn;
    }
    if (lane < 4) {
        mx[node * 4 + lane] = m;
        sv[node * 4 + lane] = (s > 0.f) ? 1.0f / s : 0.f;
    }
}

// ---------------- K7: src-side gather; att recomputed on the fly ----------------
__global__ __launch_bounds__(256) void k_gather(const unsigned short* __restrict__ FS,
                                                const int* __restrict__ offs_src,
                                                const float* __restrict__ el,
                                                const float* __restrict__ er,
                                                const float* __restrict__ mx,
                                                const float* __restrict__ sv,
                                                const float* __restrict__ Zp,
                                                float* __restrict__ out, int N)
{
    int wave = threadIdx.x >> 6;
    int lane = threadIdx.x & 63;
    int node = blockIdx.x * 4 + wave;
    if (node >= N) return;
    int start = offs_src[node], end = offs_src[node + 1];
    int h = lane & 3;
    float el_h = el[node * 4 + h];
    float acc0 = 0.f, acc1 = 0.f;
    int j = start;
    for (; j + 1 < end; j += 2) {
        int d0 = FS[j], d1 = FS[j + 1];
        float a0 = el_h + er[d0 * 4 + h];
        float a1 = el_h + er[d1 * 4 + h];
        a0 = a0 > 0.f ? a0 : 0.01f * a0;
        a1 = a1 > 0.f ? a1 : 0.01f * a1;
        float t0 = __expf(a0 - mx[d0 * 4 + h]) * sv[d0 * 4 + h];
        float t1 = __expf(a1 - mx[d1 * 4 + h]) * sv[d1 * 4 + h];
        float z00 = Zp[(size_t)d0 * CH + lane];
        float z01 = Zp[(size_t)d0 * CH + 64 + lane];
        float z10 = Zp[(size_t)d1 * CH + lane];
        float z11 = Zp[(size_t)d1 * CH + 64 + lane];
        acc0 += t0 * z00 + t1 * z10;
        acc1 += t0 * z01 + t1 * z11;
    }
    if (j < end) {
        int d0 = FS[j];
        float a0 = el_h + er[d0 * 4 + h];
        a0 = a0 > 0.f ? a0 : 0.01f * a0;
        float t0 = __expf(a0 - mx[d0 * 4 + h]) * sv[d0 * 4 + h];
        acc0 += t0 * Zp[(size_t)d0 * CH + lane];
        acc1 += t0 * Zp[(size_t)d0 * CH + 64 + lane];
    }
    out[(size_t)node * CH + lane]      = acc0;
    out[(size_t)node * CH + 64 + lane] = acc1;
}

static inline char* align16(char* p) {
    return (char*)(((uintptr_t)p + 15) & ~(uintptr_t)15);
}

extern "C" void kernel_launch(void* const* d_in, const int* in_sizes, int n_in,
                              void* d_out, int out_size, void* d_ws, size_t ws_size,
                              hipStream_t stream)
{
    const int*   idx = (const int*)d_in[0];
    const float* Z   = (const float*)d_in[2];
    const float* W   = (const float*)d_in[3];
    const float* b   = (const float*)d_in[4];
    const float* al  = (const float*)d_in[5];
    const float* ar  = (const float*)d_in[6];
    float* out = (float*)d_out;

    const int E = in_sizes[0] / 2;
    const int N = in_sizes[2] / KIN;
    const int NBK = (N + 63) >> 6;      // 64-node buckets

    char* p = (char*)d_ws;
    float* Zp = (float*)p;               p = align16(p + sizeof(float) * (size_t)N * CH);
    float* el = (float*)p;               p = align16(p + sizeof(float) * (size_t)N * 4);
    float* er = (float*)p;               p = align16(p + sizeof(float) * (size_t)N * 4);
    float* mx = (float*)p;               p = align16(p + sizeof(float) * (size_t)N * 4);
    float* sv = (float*)p;               p = align16(p + sizeof(float) * (size_t)N * 4);
    int* H    = (int*)p;                 p = align16(p + sizeof(int) * (size_t)2 * NBK * BH);
    int* btot = (int*)p;                 p = align16(p + sizeof(int) * (size_t)2 * NBK);
    int* bbase = (int*)p;                p = align16(p + sizeof(int) * ((size_t)2 * NBK + 1));
    unsigned* C = (unsigned*)p;          p = align16(p + sizeof(unsigned) * (size_t)2 * E);
    unsigned short* FS = (unsigned short*)p;  p = align16(p + sizeof(unsigned short) * (size_t)E);
    unsigned short* FD = (unsigned short*)p;  p = align16(p + sizeof(unsigned short) * (size_t)E);
    int* offs_src = (int*)p;             p = align16(p + sizeof(int) * ((size_t)N + 1));
    int* offs_dst = (int*)p;             p = align16(p + sizeof(int) * ((size_t)N + 1));

    k_gemm  <<<(N + 31) / 32, 128, 0, stream>>>(Z, W, b, Zp, N);
    k_logits<<<(N + 3) / 4,   256, 0, stream>>>(Zp, al, ar, el, er, N);
    k_hist  <<<BH, 256, 0, stream>>>(idx, H, E, NBK);
    k_bsum  <<<2 * NBK, 128, 0, stream>>>(H, btot);
    k_scan  <<<1, 1024, 0, stream>>>(btot, bbase, 2 * NBK);
    k_bbase <<<2 * NBK, 128, 0, stream>>>(H, bbase);
    k_coarse<<<BH, 256, 0, stream>>>(idx, H, C, E, NBK);
    k_fine  <<<2 * NBK, 256, 0, stream>>>(C, bbase, FS, FD, offs_src, offs_dst, E, N, NBK);
    k_softmax<<<(N + 3) / 4, 256, 0, stream>>>(FD, offs_dst, el, er, mx, sv, N);
    k_gather <<<(N + 3) / 4, 256, 0, stream>>>(FS, offs_src, el, er, mx, sv, Zp, out, N);
}